// Round 5
// baseline (941.470 us; speedup 1.0000x reference)
//
#include <hip/hip_runtime.h>

#define N_NODES 100000
#define N_EDGES 1600000
#define N_LABEL 200000
#define D 128

#define SCAN_BLOCKS ((N_NODES + 255) / 256)   // 391

// ---- bf16 helpers (round-to-nearest-even) ----
static __device__ __forceinline__ unsigned short f2bf(float f) {
    unsigned u = __float_as_uint(f);
    u += 0x7fffu + ((u >> 16) & 1u);
    return (unsigned short)(u >> 16);
}
static __device__ __forceinline__ float bf2f_lo(unsigned p) {
    return __uint_as_float(p << 16);
}
static __device__ __forceinline__ float bf2f_hi(unsigned p) {
    return __uint_as_float(p & 0xffff0000u);
}

// ---------------- prep: w = rowsum(lin_W), c = sum(lin_b) ----------------
__global__ void k_prep(const float* __restrict__ linW, const float* __restrict__ linb,
                       float* __restrict__ wv, float* __restrict__ cval) {
    int t = threadIdx.x;  // 128 threads
    float s = 0.f;
    for (int j = 0; j < D; ++j) s += linW[t * D + j];
    wv[t] = s;
    __shared__ float red[128];
    red[t] = linb[t];
    __syncthreads();
    for (int st = 64; st > 0; st >>= 1) {
        if (t < st) red[t] += red[t + st];
        __syncthreads();
    }
    if (t == 0) *cval = red[0];
}

// ---------------- init: deg=1 (self loop), offs=0, fill=0 ----------------
__global__ void k_init(float* __restrict__ deg, int* __restrict__ offs,
                       int* __restrict__ fill) {
    int i = blockIdx.x * 256 + threadIdx.x;
    if (i < N_NODES) { deg[i] = 1.0f; fill[i] = 0; }
    if (i < N_NODES + 4) offs[i] = 0;
}

// fused: degree accumulate + in-degree count (one pass over edge index)
__global__ void k_countdeg(const int* __restrict__ ei, const float* __restrict__ ew,
                           float* __restrict__ deg, int* __restrict__ cnt) {
    int e = blockIdx.x * 256 + threadIdx.x;
    if (e < N_EDGES) {
        int d = ei[N_EDGES + e];
        atomicAdd(&deg[d], ew[e]);
        atomicAdd(&cnt[d], 1);
    }
}

__global__ void k_dinv(float* __restrict__ deg) {
    int i = blockIdx.x * 256 + threadIdx.x;
    if (i < N_NODES) deg[i] = rsqrtf(deg[i]);
}

// ---------------- CSR build: scan ----------------
__global__ void k_scan1(int* __restrict__ offs, int* __restrict__ bsum) {
    __shared__ int sm[256];
    int tid = threadIdx.x;
    int i = blockIdx.x * 256 + tid;
    int v = (i < N_NODES) ? offs[i] : 0;
    sm[tid] = v;
    __syncthreads();
    for (int st = 1; st < 256; st <<= 1) {
        int add = (tid >= st) ? sm[tid - st] : 0;
        __syncthreads();
        sm[tid] += add;
        __syncthreads();
    }
    if (i < N_NODES) offs[i] = sm[tid] - v;  // exclusive
    if (tid == 255) bsum[blockIdx.x] = sm[255];
}

__global__ void k_scan2(int* __restrict__ bsum) {
    __shared__ int sm[512];
    int tid = threadIdx.x;
    int v = (tid < SCAN_BLOCKS) ? bsum[tid] : 0;
    sm[tid] = v;
    __syncthreads();
    for (int st = 1; st < 512; st <<= 1) {
        int add = (tid >= st) ? sm[tid - st] : 0;
        __syncthreads();
        sm[tid] += add;
        __syncthreads();
    }
    if (tid < SCAN_BLOCKS) bsum[tid] = sm[tid] - v;  // exclusive
}

__global__ void k_scan3(int* __restrict__ offs, const int* __restrict__ bsum) {
    int i = blockIdx.x * 256 + threadIdx.x;
    if (i < N_NODES) offs[i] += bsum[i >> 8];
    if (i == 0) offs[N_NODES] = N_EDGES;
}

// scatter edges into CSR, computing norm on the fly
__global__ void k_scatter(const int* __restrict__ ei, const float* __restrict__ ew,
                          const float* __restrict__ dinv, const int* __restrict__ offs,
                          int* __restrict__ fill, int* __restrict__ csr_src,
                          float* __restrict__ csr_w) {
    int e = blockIdx.x * 256 + threadIdx.x;
    if (e < N_EDGES) {
        int s = ei[e];
        int d = ei[N_EDGES + e];
        float nm = dinv[s] * ew[e] * dinv[d];
        int pos = offs[d] + atomicAdd(&fill[d], 1);
        csr_src[pos] = s;
        csr_w[pos] = nm;
    }
}

// ---------------- GEMM: H(bf16, TILED) = X(f32) @ W(f32) ----------------
// H layout: H[tile][node][16]  (tile = col/16), ushort units
__global__ __launch_bounds__(256) void k_gemm(const float* __restrict__ X,
                                              const float* __restrict__ W,
                                              unsigned short* __restrict__ H) {
    __shared__ float xs[64][128];
    __shared__ float ws[16][128];
    int tid = threadIdx.x;
    int rowBase = blockIdx.x * 64;

#pragma unroll
    for (int i = 0; i < 8; ++i) {
        int idx = tid + i * 256;
        int r = idx >> 5;
        int cc = (idx & 31) * 4;
        int gr = rowBase + r;
        float4 v = make_float4(0.f, 0.f, 0.f, 0.f);
        if (gr < N_NODES) v = *(const float4*)&X[(size_t)gr * D + cc];
        *(float4*)&xs[r][cc] = v;
    }

    int rg = tid >> 5;       // 0..7
    int cg = tid & 31;       // 0..31
    int c0 = cg * 4;
    float acc[8][4] = {};

    for (int k0 = 0; k0 < D; k0 += 16) {
        __syncthreads();  // protect ws reuse (covers xs staging on first iter)
#pragma unroll
        for (int i = 0; i < 2; ++i) {
            int idx = tid + i * 256;
            int r = idx >> 5;
            int cc = (idx & 31) * 4;
            *(float4*)&ws[r][cc] = *(const float4*)&W[(k0 + r) * D + cc];
        }
        __syncthreads();
#pragma unroll
        for (int kk = 0; kk < 16; kk += 4) {
            float4 w0 = *(float4*)&ws[kk + 0][c0];
            float4 w1 = *(float4*)&ws[kk + 1][c0];
            float4 w2 = *(float4*)&ws[kk + 2][c0];
            float4 w3 = *(float4*)&ws[kk + 3][c0];
#pragma unroll
            for (int r = 0; r < 8; ++r) {
                float4 xv = *(float4*)&xs[rg * 8 + r][k0 + kk];
                acc[r][0] += xv.x * w0.x + xv.y * w1.x + xv.z * w2.x + xv.w * w3.x;
                acc[r][1] += xv.x * w0.y + xv.y * w1.y + xv.z * w2.y + xv.w * w3.y;
                acc[r][2] += xv.x * w0.z + xv.y * w1.z + xv.z * w2.z + xv.w * w3.z;
                acc[r][3] += xv.x * w0.w + xv.y * w1.w + xv.z * w2.w + xv.w * w3.w;
            }
        }
    }

    int tile = c0 >> 4;
    int within = c0 & 15;
#pragma unroll
    for (int r = 0; r < 8; ++r) {
        int gr = rowBase + rg * 8 + r;
        if (gr < N_NODES) {
            ushort4 o;
            o.x = f2bf(acc[r][0]);
            o.y = f2bf(acc[r][1]);
            o.z = f2bf(acc[r][2]);
            o.w = f2bf(acc[r][3]);
            *(ushort4*)&H[((size_t)tile * N_NODES + gr) * 16 + within] = o;
        }
    }
}

// ---------------- fused aggregation, XCD-pinned feature tiles ----------------
// h tiled: ht[tile][node][8] (uint = 2 bf16). blockIdx = nb*8 + tile, so
// tile == blockIdx%8 lands on a fixed XCD under round-robin dispatch ->
// each XCD gathers only its 3.2 MB slice (L2-resident).
// Wave: lane = eslot*8 + fp; 8 edges in flight; shuffle-reduce over eslot.
template <bool OUT_BF>
__global__ __launch_bounds__(256) void k_agg(const unsigned* __restrict__ h,
                                             const float* __restrict__ dinv,
                                             const int* __restrict__ offs,
                                             const int* __restrict__ csr_src,
                                             const float* __restrict__ csr_w,
                                             const float* __restrict__ bias,
                                             void* __restrict__ out) {
    int tile = blockIdx.x & 7;
    int nb   = blockIdx.x >> 3;
    int wid  = threadIdx.x >> 6;
    int lane = threadIdx.x & 63;
    int node = nb * 4 + wid;
    if (node >= N_NODES) return;

    int fp = lane & 7;   // feature pair 0..7 (2 feats each)
    int es = lane >> 3;  // edge slot 0..7

    const unsigned* ht = h + (size_t)tile * N_NODES * 8;
    float ax = 0.f, ay = 0.f;
    int p0 = offs[node], p1 = offs[node + 1];
    for (int p = p0; p < p1; p += 8) {
        int pe = p + es;
        bool valid = pe < p1;
        int idx = valid ? pe : p0;           // p0 < p1 inside loop -> safe
        int s = csr_src[idx];
        float w = valid ? csr_w[idx] : 0.f;
        unsigned hv = ht[(size_t)s * 8 + fp];
        ax += w * bf2f_lo(hv);
        ay += w * bf2f_hi(hv);
    }
    // reduce over edge slots (lane = es*8 + fp)
    ax += __shfl_down(ax, 32, 64);
    ay += __shfl_down(ay, 32, 64);
    ax += __shfl_down(ax, 16, 64);
    ay += __shfl_down(ay, 16, 64);
    ax += __shfl_down(ax, 8, 64);
    ay += __shfl_down(ay, 8, 64);

    if (es == 0) {
        float dn = dinv[node];
        dn *= dn;
        unsigned sv = ht[(size_t)node * 8 + fp];
        ax += dn * bf2f_lo(sv);
        ay += dn * bf2f_hi(sv);
        float2 bb = *(const float2*)&bias[tile * 16 + fp * 2];
        ax = fmaxf(ax + bb.x, 0.f);
        ay = fmaxf(ay + bb.y, 0.f);
        if (OUT_BF) {
            unsigned o = (unsigned)f2bf(ax) | ((unsigned)f2bf(ay) << 16);
            ((unsigned*)out)[(size_t)node * 64 + tile * 8 + fp] = o;  // row-major bf16
        } else {
            *(float2*)&((float*)out)[(size_t)node * D + tile * 16 + fp * 2] =
                make_float2(ax, ay);  // row-major f32
        }
    }
}

// ---------------- final: res[l] = sum_k o2[a][k]*o2[b][k]*w[k] + c ----------------
__global__ void k_final(const int* __restrict__ eli, const unsigned* __restrict__ o2,
                        const float* __restrict__ wv, const float* __restrict__ cval,
                        float* __restrict__ res) {
    unsigned g = blockIdx.x * 256 + threadIdx.x;
    int l = g >> 6;
    int t = g & 63;
    if (l < N_LABEL) {
        int a = eli[l];
        int b = eli[N_LABEL + l];
        unsigned ua = o2[(size_t)a * 64 + t];
        unsigned ub = o2[(size_t)b * 64 + t];
        float2 w2 = *(const float2*)&wv[t * 2];
        float s = bf2f_lo(ua) * bf2f_lo(ub) * w2.x + bf2f_hi(ua) * bf2f_hi(ub) * w2.y;
#pragma unroll
        for (int st = 32; st > 0; st >>= 1) s += __shfl_down(s, st, 64);
        if (t == 0) res[l] = s + *cval;
    }
}

extern "C" void kernel_launch(void* const* d_in, const int* in_sizes, int n_in,
                              void* d_out, int out_size, void* d_ws, size_t ws_size,
                              hipStream_t stream) {
    const float* x    = (const float*)d_in[0];
    const int*   ei   = (const int*)d_in[1];
    const float* ew   = (const float*)d_in[2];
    const int*   eli  = (const int*)d_in[3];
    const float* W1   = (const float*)d_in[4];
    const float* b1   = (const float*)d_in[5];
    const float* W2   = (const float*)d_in[6];
    const float* b2   = (const float*)d_in[7];
    const float* linW = (const float*)d_in[8];
    const float* linb = (const float*)d_in[9];
    float* res = (float*)d_out;

    // workspace layout (16B alignment maintained for all row buffers)
    float*    ws      = (float*)d_ws;
    float*    dinv    = ws;                              // N
    int*      offs    = (int*)(dinv + N_NODES);          // N+4
    int*      fill    = offs + N_NODES + 4;              // N
    int*      bsum    = fill + N_NODES;                  // 512
    int*      csr_src = bsum + 512;                      // E
    float*    csr_w   = (float*)(csr_src + N_EDGES);     // E
    unsigned* h_bf    = (unsigned*)(csr_w + N_EDGES);    // N*64 uints (bf16 h, tiled)
    float*    agg     = (float*)(h_bf + (size_t)N_NODES * 64);   // N*D f32
    unsigned* out2    = (unsigned*)(agg + (size_t)N_NODES * D);  // N*64 uints
    float*    wv      = (float*)(out2 + (size_t)N_NODES * 64);   // D
    float*    cval    = wv + D;                          // 1

    k_prep<<<1, 128, 0, stream>>>(linW, linb, wv, cval);

    // degrees + CSR counts (fused pass), then dinv
    k_init<<<(N_NODES + 4 + 255) / 256, 256, 0, stream>>>(dinv, offs, fill);
    k_countdeg<<<(N_EDGES + 255) / 256, 256, 0, stream>>>(ei, ew, dinv, offs);
    k_dinv<<<(N_NODES + 255) / 256, 256, 0, stream>>>(dinv);

    // scan + scatter
    k_scan1<<<SCAN_BLOCKS, 256, 0, stream>>>(offs, bsum);
    k_scan2<<<1, 512, 0, stream>>>(bsum);
    k_scan3<<<SCAN_BLOCKS, 256, 0, stream>>>(offs, bsum);
    k_scatter<<<(N_EDGES + 255) / 256, 256, 0, stream>>>(ei, ew, dinv, offs, fill,
                                                         csr_src, csr_w);

    const int AGG_GRID = ((N_NODES + 3) / 4) * 8;

    // layer 1: h = x@W1 (bf16 tiled), agg = A_norm·h + b1, relu (f32 row-major)
    k_gemm<<<(N_NODES + 63) / 64, 256, 0, stream>>>(x, W1, (unsigned short*)h_bf);
    k_agg<false><<<AGG_GRID, 256, 0, stream>>>(h_bf, dinv, offs, csr_src,
                                               csr_w, b1, agg);

    // layer 2: h = agg@W2 (bf16 tiled), out2 = A_norm·h + b2, relu (bf16 row-major)
    k_gemm<<<(N_NODES + 63) / 64, 256, 0, stream>>>(agg, W2, (unsigned short*)h_bf);
    k_agg<true><<<AGG_GRID, 256, 0, stream>>>(h_bf, dinv, offs, csr_src,
                                              csr_w, b2, out2);

    // final
    k_final<<<(N_LABEL * 64 + 255) / 256, 256, 0, stream>>>(eli, out2, wv, cval, res);
}

// Round 6
// 603.773 us; speedup vs baseline: 1.5593x; 1.5593x over previous
//
#include <hip/hip_runtime.h>

#define N_NODES 100000
#define N_EDGES 1600000
#define N_LABEL 200000
#define D 128

#define SCAN_BLOCKS ((N_NODES + 255) / 256)   // 391

// ---- bf16 helpers (round-to-nearest-even) ----
static __device__ __forceinline__ unsigned short f2bf(float f) {
    unsigned u = __float_as_uint(f);
    u += 0x7fffu + ((u >> 16) & 1u);
    return (unsigned short)(u >> 16);
}
static __device__ __forceinline__ float bf2f_lo(unsigned p) {
    return __uint_as_float(p << 16);
}
static __device__ __forceinline__ float bf2f_hi(unsigned p) {
    return __uint_as_float(p & 0xffff0000u);
}

// ---------------- prep: w = rowsum(lin_W), c = sum(lin_b) ----------------
__global__ void k_prep(const float* __restrict__ linW, const float* __restrict__ linb,
                       float* __restrict__ wv, float* __restrict__ cval) {
    int t = threadIdx.x;  // 128 threads
    float s = 0.f;
    for (int j = 0; j < D; ++j) s += linW[t * D + j];
    wv[t] = s;
    __shared__ float red[128];
    red[t] = linb[t];
    __syncthreads();
    for (int st = 64; st > 0; st >>= 1) {
        if (t < st) red[t] += red[t + st];
        __syncthreads();
    }
    if (t == 0) *cval = red[0];
}

// ---------------- init: deg=1 (self loop), offs=0, fill=0 ----------------
__global__ void k_init(float* __restrict__ deg, int* __restrict__ offs,
                       int* __restrict__ fill) {
    int i = blockIdx.x * 256 + threadIdx.x;
    if (i < N_NODES) { deg[i] = 1.0f; fill[i] = 0; }
    if (i < N_NODES + 4) offs[i] = 0;
}

// fused: degree accumulate + in-degree count (one pass over edge index)
__global__ void k_countdeg(const int* __restrict__ ei, const float* __restrict__ ew,
                           float* __restrict__ deg, int* __restrict__ cnt) {
    int e = blockIdx.x * 256 + threadIdx.x;
    if (e < N_EDGES) {
        int d = ei[N_EDGES + e];
        atomicAdd(&deg[d], ew[e]);
        atomicAdd(&cnt[d], 1);
    }
}

__global__ void k_dinv(float* __restrict__ deg) {
    int i = blockIdx.x * 256 + threadIdx.x;
    if (i < N_NODES) deg[i] = rsqrtf(deg[i]);
}

// ---------------- CSR build: scan ----------------
__global__ void k_scan1(int* __restrict__ offs, int* __restrict__ bsum) {
    __shared__ int sm[256];
    int tid = threadIdx.x;
    int i = blockIdx.x * 256 + tid;
    int v = (i < N_NODES) ? offs[i] : 0;
    sm[tid] = v;
    __syncthreads();
    for (int st = 1; st < 256; st <<= 1) {
        int add = (tid >= st) ? sm[tid - st] : 0;
        __syncthreads();
        sm[tid] += add;
        __syncthreads();
    }
    if (i < N_NODES) offs[i] = sm[tid] - v;  // exclusive
    if (tid == 255) bsum[blockIdx.x] = sm[255];
}

__global__ void k_scan2(int* __restrict__ bsum) {
    __shared__ int sm[512];
    int tid = threadIdx.x;
    int v = (tid < SCAN_BLOCKS) ? bsum[tid] : 0;
    sm[tid] = v;
    __syncthreads();
    for (int st = 1; st < 512; st <<= 1) {
        int add = (tid >= st) ? sm[tid - st] : 0;
        __syncthreads();
        sm[tid] += add;
        __syncthreads();
    }
    if (tid < SCAN_BLOCKS) bsum[tid] = sm[tid] - v;  // exclusive
}

__global__ void k_scan3(int* __restrict__ offs, const int* __restrict__ bsum) {
    int i = blockIdx.x * 256 + threadIdx.x;
    if (i < N_NODES) offs[i] += bsum[i >> 8];
    if (i == 0) offs[N_NODES] = N_EDGES;
}

// scatter edges into CSR, computing norm on the fly
__global__ void k_scatter(const int* __restrict__ ei, const float* __restrict__ ew,
                          const float* __restrict__ dinv, const int* __restrict__ offs,
                          int* __restrict__ fill, int* __restrict__ csr_src,
                          float* __restrict__ csr_w) {
    int e = blockIdx.x * 256 + threadIdx.x;
    if (e < N_EDGES) {
        int s = ei[e];
        int d = ei[N_EDGES + e];
        float nm = dinv[s] * ew[e] * dinv[d];
        int pos = offs[d] + atomicAdd(&fill[d], 1);
        csr_src[pos] = s;
        csr_w[pos] = nm;
    }
}

// ---------------- GEMM: H(bf16) = X(f32) @ W(f32) ----------------
__global__ __launch_bounds__(256) void k_gemm(const float* __restrict__ X,
                                              const float* __restrict__ W,
                                              unsigned short* __restrict__ H) {
    __shared__ float xs[64][128];
    __shared__ float ws[16][128];
    int tid = threadIdx.x;
    int rowBase = blockIdx.x * 64;

#pragma unroll
    for (int i = 0; i < 8; ++i) {
        int idx = tid + i * 256;
        int r = idx >> 5;
        int cc = (idx & 31) * 4;
        int gr = rowBase + r;
        float4 v = make_float4(0.f, 0.f, 0.f, 0.f);
        if (gr < N_NODES) v = *(const float4*)&X[(size_t)gr * D + cc];
        *(float4*)&xs[r][cc] = v;
    }

    int rg = tid >> 5;       // 0..7
    int cg = tid & 31;       // 0..31
    int c0 = cg * 4;
    float acc[8][4] = {};

    for (int k0 = 0; k0 < D; k0 += 16) {
        __syncthreads();  // protect ws reuse (covers xs staging on first iter)
#pragma unroll
        for (int i = 0; i < 2; ++i) {
            int idx = tid + i * 256;
            int r = idx >> 5;
            int cc = (idx & 31) * 4;
            *(float4*)&ws[r][cc] = *(const float4*)&W[(k0 + r) * D + cc];
        }
        __syncthreads();
#pragma unroll
        for (int kk = 0; kk < 16; kk += 4) {
            float4 w0 = *(float4*)&ws[kk + 0][c0];
            float4 w1 = *(float4*)&ws[kk + 1][c0];
            float4 w2 = *(float4*)&ws[kk + 2][c0];
            float4 w3 = *(float4*)&ws[kk + 3][c0];
#pragma unroll
            for (int r = 0; r < 8; ++r) {
                float4 xv = *(float4*)&xs[rg * 8 + r][k0 + kk];
                acc[r][0] += xv.x * w0.x + xv.y * w1.x + xv.z * w2.x + xv.w * w3.x;
                acc[r][1] += xv.x * w0.y + xv.y * w1.y + xv.z * w2.y + xv.w * w3.y;
                acc[r][2] += xv.x * w0.z + xv.y * w1.z + xv.z * w2.z + xv.w * w3.z;
                acc[r][3] += xv.x * w0.w + xv.y * w1.w + xv.z * w2.w + xv.w * w3.w;
            }
        }
    }

#pragma unroll
    for (int r = 0; r < 8; ++r) {
        int gr = rowBase + rg * 8 + r;
        if (gr < N_NODES) {
            ushort4 o;
            o.x = f2bf(acc[r][0]);
            o.y = f2bf(acc[r][1]);
            o.z = f2bf(acc[r][2]);
            o.w = f2bf(acc[r][3]);
            *(ushort4*)&H[(size_t)gr * D + c0] = o;
        }
    }
}

// ---------------- fused aggregation: self + gather + bias + relu ----------------
// one wave per node; h is bf16 row-major (uint = 2 feats per lane).
// Edge loop processes MASKED GROUPS OF 4: issue 4 independent index loads,
// then 4 independent row gathers -> 4 memory ops in flight instead of a
// serial dependent chain (latency-bound fix; no extra traffic).
template <bool OUT_BF>
__global__ __launch_bounds__(256) void k_agg(const unsigned* __restrict__ h,
                                             const float* __restrict__ dinv,
                                             const int* __restrict__ offs,
                                             const int* __restrict__ csr_src,
                                             const float* __restrict__ csr_w,
                                             const float* __restrict__ bias,
                                             void* __restrict__ out) {
    int wid = threadIdx.x >> 6;
    int lane = threadIdx.x & 63;
    int node = blockIdx.x * 4 + wid;
    if (node >= N_NODES) return;
    float dn = dinv[node];
    dn *= dn;
    unsigned sv = h[(size_t)node * 64 + lane];
    float ax = bf2f_lo(sv) * dn, ay = bf2f_hi(sv) * dn;
    int p0 = offs[node], p1 = offs[node + 1];

    for (int p = p0; p < p1; p += 4) {
        // masked group of 4 (idx=p0 is safe: loop body implies p0 < p1)
        bool v1 = p + 1 < p1, v2 = p + 2 < p1, v3 = p + 3 < p1;
        int i0 = p;
        int i1 = v1 ? p + 1 : p0;
        int i2 = v2 ? p + 2 : p0;
        int i3 = v3 ? p + 3 : p0;
        int s0 = csr_src[i0];
        int s1 = csr_src[i1];
        int s2 = csr_src[i2];
        int s3 = csr_src[i3];
        float w0 = csr_w[i0];
        float w1 = v1 ? csr_w[i1] : 0.f;
        float w2 = v2 ? csr_w[i2] : 0.f;
        float w3 = v3 ? csr_w[i3] : 0.f;
        unsigned h0 = h[(size_t)s0 * 64 + lane];
        unsigned h1 = h[(size_t)s1 * 64 + lane];
        unsigned h2 = h[(size_t)s2 * 64 + lane];
        unsigned h3 = h[(size_t)s3 * 64 + lane];
        ax += w0 * bf2f_lo(h0) + w1 * bf2f_lo(h1) + w2 * bf2f_lo(h2) + w3 * bf2f_lo(h3);
        ay += w0 * bf2f_hi(h0) + w1 * bf2f_hi(h1) + w2 * bf2f_hi(h2) + w3 * bf2f_hi(h3);
    }

    float2 bb = *(const float2*)&bias[lane * 2];
    ax = fmaxf(ax + bb.x, 0.f);
    ay = fmaxf(ay + bb.y, 0.f);
    if (OUT_BF) {
        unsigned o = (unsigned)f2bf(ax) | ((unsigned)f2bf(ay) << 16);
        ((unsigned*)out)[(size_t)node * 64 + lane] = o;
    } else {
        *(float2*)&((float*)out)[(size_t)node * D + lane * 2] = make_float2(ax, ay);
    }
}

// ---------------- final: res[l] = sum_k o2[a][k]*o2[b][k]*w[k] + c ----------------
__global__ void k_final(const int* __restrict__ eli, const unsigned* __restrict__ o2,
                        const float* __restrict__ wv, const float* __restrict__ cval,
                        float* __restrict__ res) {
    unsigned g = blockIdx.x * 256 + threadIdx.x;
    int l = g >> 6;
    int t = g & 63;
    if (l < N_LABEL) {
        int a = eli[l];
        int b = eli[N_LABEL + l];
        unsigned ua = o2[(size_t)a * 64 + t];
        unsigned ub = o2[(size_t)b * 64 + t];
        float2 w2 = *(const float2*)&wv[t * 2];
        float s = bf2f_lo(ua) * bf2f_lo(ub) * w2.x + bf2f_hi(ua) * bf2f_hi(ub) * w2.y;
#pragma unroll
        for (int st = 32; st > 0; st >>= 1) s += __shfl_down(s, st, 64);
        if (t == 0) res[l] = s + *cval;
    }
}

extern "C" void kernel_launch(void* const* d_in, const int* in_sizes, int n_in,
                              void* d_out, int out_size, void* d_ws, size_t ws_size,
                              hipStream_t stream) {
    const float* x    = (const float*)d_in[0];
    const int*   ei   = (const int*)d_in[1];
    const float* ew   = (const float*)d_in[2];
    const int*   eli  = (const int*)d_in[3];
    const float* W1   = (const float*)d_in[4];
    const float* b1   = (const float*)d_in[5];
    const float* W2   = (const float*)d_in[6];
    const float* b2   = (const float*)d_in[7];
    const float* linW = (const float*)d_in[8];
    const float* linb = (const float*)d_in[9];
    float* res = (float*)d_out;

    // workspace layout (16B alignment maintained for all row buffers)
    float*    ws      = (float*)d_ws;
    float*    dinv    = ws;                              // N
    int*      offs    = (int*)(dinv + N_NODES);          // N+4
    int*      fill    = offs + N_NODES + 4;              // N
    int*      bsum    = fill + N_NODES;                  // 512
    int*      csr_src = bsum + 512;                      // E
    float*    csr_w   = (float*)(csr_src + N_EDGES);     // E
    unsigned* h_bf    = (unsigned*)(csr_w + N_EDGES);    // N*64 uints (bf16 h)
    float*    agg     = (float*)(h_bf + (size_t)N_NODES * 64);   // N*D f32
    unsigned* out2    = (unsigned*)(agg + (size_t)N_NODES * D);  // N*64 uints
    float*    wv      = (float*)(out2 + (size_t)N_NODES * 64);   // D
    float*    cval    = wv + D;                          // 1

    k_prep<<<1, 128, 0, stream>>>(linW, linb, wv, cval);

    // degrees + CSR counts (fused pass), then dinv
    k_init<<<(N_NODES + 4 + 255) / 256, 256, 0, stream>>>(dinv, offs, fill);
    k_countdeg<<<(N_EDGES + 255) / 256, 256, 0, stream>>>(ei, ew, dinv, offs);
    k_dinv<<<(N_NODES + 255) / 256, 256, 0, stream>>>(dinv);

    // scan + scatter
    k_scan1<<<SCAN_BLOCKS, 256, 0, stream>>>(offs, bsum);
    k_scan2<<<1, 512, 0, stream>>>(bsum);
    k_scan3<<<SCAN_BLOCKS, 256, 0, stream>>>(offs, bsum);
    k_scatter<<<(N_EDGES + 255) / 256, 256, 0, stream>>>(ei, ew, dinv, offs, fill,
                                                         csr_src, csr_w);

    // layer 1: h = x@W1 (bf16), agg = A_norm·h + b1, relu (fp32 out)
    k_gemm<<<(N_NODES + 63) / 64, 256, 0, stream>>>(x, W1, (unsigned short*)h_bf);
    k_agg<false><<<(N_NODES + 3) / 4, 256, 0, stream>>>(h_bf, dinv, offs, csr_src,
                                                        csr_w, b1, agg);

    // layer 2: h = agg@W2 (bf16), out2 = A_norm·h + b2, relu (bf16 out)
    k_gemm<<<(N_NODES + 63) / 64, 256, 0, stream>>>(agg, W2, (unsigned short*)h_bf);
    k_agg<true><<<(N_NODES + 3) / 4, 256, 0, stream>>>(h_bf, dinv, offs, csr_src,
                                                       csr_w, b2, out2);

    // final
    k_final<<<(N_LABEL * 64 + 255) / 256, 256, 0, stream>>>(eli, out2, wv, cval, res);
}

// Round 7
// 483.128 us; speedup vs baseline: 1.9487x; 1.2497x over previous
//
#include <hip/hip_runtime.h>

#define N_NODES 100000
#define N_EDGES 1600000
#define N_LABEL 200000
#define D 128

#define SCAN_BLOCKS ((N_NODES + 255) / 256)   // 391

// ---- bf16 helpers (round-to-nearest-even) ----
static __device__ __forceinline__ unsigned short f2bf(float f) {
    unsigned u = __float_as_uint(f);
    u += 0x7fffu + ((u >> 16) & 1u);
    return (unsigned short)(u >> 16);
}
static __device__ __forceinline__ float bf2f_lo(unsigned p) {
    return __uint_as_float(p << 16);
}
static __device__ __forceinline__ float bf2f_hi(unsigned p) {
    return __uint_as_float(p & 0xffff0000u);
}

// ---------------- prep: w = rowsum(lin_W), c = sum(lin_b) ----------------
__global__ void k_prep(const float* __restrict__ linW, const float* __restrict__ linb,
                       float* __restrict__ wv, float* __restrict__ cval) {
    int t = threadIdx.x;  // 128 threads
    float s = 0.f;
    for (int j = 0; j < D; ++j) s += linW[t * D + j];
    wv[t] = s;
    __shared__ float red[128];
    red[t] = linb[t];
    __syncthreads();
    for (int st = 64; st > 0; st >>= 1) {
        if (t < st) red[t] += red[t + st];
        __syncthreads();
    }
    if (t == 0) *cval = red[0];
}

// ---------------- init: offs=0 ----------------
__global__ void k_init(int* __restrict__ offs) {
    int i = blockIdx.x * 256 + threadIdx.x;
    if (i < N_NODES + 4) offs[i] = 0;
}

// count in-degree; the SAME atomic returns each edge's rank within its dst
__global__ void k_count(const int* __restrict__ ei, int* __restrict__ cnt,
                        int* __restrict__ rank) {
    int e = blockIdx.x * 256 + threadIdx.x;
    if (e < N_EDGES) rank[e] = atomicAdd(&cnt[ei[N_EDGES + e]], 1);
}

// ---------------- CSR build: scan ----------------
__global__ void k_scan1(int* __restrict__ offs, int* __restrict__ bsum) {
    __shared__ int sm[256];
    int tid = threadIdx.x;
    int i = blockIdx.x * 256 + tid;
    int v = (i < N_NODES) ? offs[i] : 0;
    sm[tid] = v;
    __syncthreads();
    for (int st = 1; st < 256; st <<= 1) {
        int add = (tid >= st) ? sm[tid - st] : 0;
        __syncthreads();
        sm[tid] += add;
        __syncthreads();
    }
    if (i < N_NODES) offs[i] = sm[tid] - v;  // exclusive
    if (tid == 255) bsum[blockIdx.x] = sm[255];
}

__global__ void k_scan2(int* __restrict__ bsum) {
    __shared__ int sm[512];
    int tid = threadIdx.x;
    int v = (tid < SCAN_BLOCKS) ? bsum[tid] : 0;
    sm[tid] = v;
    __syncthreads();
    for (int st = 1; st < 512; st <<= 1) {
        int add = (tid >= st) ? sm[tid - st] : 0;
        __syncthreads();
        sm[tid] += add;
        __syncthreads();
    }
    if (tid < SCAN_BLOCKS) bsum[tid] = sm[tid] - v;  // exclusive
}

__global__ void k_scan3(int* __restrict__ offs, const int* __restrict__ bsum) {
    int i = blockIdx.x * 256 + threadIdx.x;
    if (i < N_NODES) offs[i] += bsum[i >> 8];
    if (i == 0) offs[N_NODES] = N_EDGES;
}

// atomic-free scatter: pos = offs[dst] + rank[e]; store src and RAW weight
__global__ void k_scatter(const int* __restrict__ ei, const float* __restrict__ ew,
                          const int* __restrict__ offs, const int* __restrict__ rank,
                          int* __restrict__ csr_src, float* __restrict__ csr_w) {
    int e = blockIdx.x * 256 + threadIdx.x;
    if (e < N_EDGES) {
        int d = ei[N_EDGES + e];
        int pos = offs[d] + rank[e];
        csr_src[pos] = ei[e];
        csr_w[pos] = ew[e];
    }
}

// deg[i] = 1 + sum of raw weights over i's CSR rows -> dinv (no atomics)
__global__ void k_degdinv(const int* __restrict__ offs, const float* __restrict__ craw,
                          float* __restrict__ dinv) {
    int i = blockIdx.x * 256 + threadIdx.x;
    if (i < N_NODES) {
        int p0 = offs[i], p1 = offs[i + 1];
        float s = 1.0f;  // self loop
        for (int p = p0; p < p1; ++p) s += craw[p];
        dinv[i] = rsqrtf(s);
    }
}

// normalize csr_w in place: w = raw * dinv[src] * dinv[dst]
__global__ void k_normw(const int* __restrict__ offs, const int* __restrict__ csr_src,
                        float* __restrict__ csr_w, const float* __restrict__ dinv) {
    int i = blockIdx.x * 256 + threadIdx.x;
    if (i < N_NODES) {
        int p0 = offs[i], p1 = offs[i + 1];
        float dv = dinv[i];
        for (int p = p0; p < p1; ++p)
            csr_w[p] = csr_w[p] * dinv[csr_src[p]] * dv;
    }
}

// ---------------- GEMM: H(bf16) = X(f32) @ W(f32) ----------------
__global__ __launch_bounds__(256) void k_gemm(const float* __restrict__ X,
                                              const float* __restrict__ W,
                                              unsigned short* __restrict__ H) {
    __shared__ float xs[64][128];
    __shared__ float ws[16][128];
    int tid = threadIdx.x;
    int rowBase = blockIdx.x * 64;

#pragma unroll
    for (int i = 0; i < 8; ++i) {
        int idx = tid + i * 256;
        int r = idx >> 5;
        int cc = (idx & 31) * 4;
        int gr = rowBase + r;
        float4 v = make_float4(0.f, 0.f, 0.f, 0.f);
        if (gr < N_NODES) v = *(const float4*)&X[(size_t)gr * D + cc];
        *(float4*)&xs[r][cc] = v;
    }

    int rg = tid >> 5;       // 0..7
    int cg = tid & 31;       // 0..31
    int c0 = cg * 4;
    float acc[8][4] = {};

    for (int k0 = 0; k0 < D; k0 += 16) {
        __syncthreads();  // protect ws reuse (covers xs staging on first iter)
#pragma unroll
        for (int i = 0; i < 2; ++i) {
            int idx = tid + i * 256;
            int r = idx >> 5;
            int cc = (idx & 31) * 4;
            *(float4*)&ws[r][cc] = *(const float4*)&W[(k0 + r) * D + cc];
        }
        __syncthreads();
#pragma unroll
        for (int kk = 0; kk < 16; kk += 4) {
            float4 w0 = *(float4*)&ws[kk + 0][c0];
            float4 w1 = *(float4*)&ws[kk + 1][c0];
            float4 w2 = *(float4*)&ws[kk + 2][c0];
            float4 w3 = *(float4*)&ws[kk + 3][c0];
#pragma unroll
            for (int r = 0; r < 8; ++r) {
                float4 xv = *(float4*)&xs[rg * 8 + r][k0 + kk];
                acc[r][0] += xv.x * w0.x + xv.y * w1.x + xv.z * w2.x + xv.w * w3.x;
                acc[r][1] += xv.x * w0.y + xv.y * w1.y + xv.z * w2.y + xv.w * w3.y;
                acc[r][2] += xv.x * w0.z + xv.y * w1.z + xv.z * w2.z + xv.w * w3.z;
                acc[r][3] += xv.x * w0.w + xv.y * w1.w + xv.z * w2.w + xv.w * w3.w;
            }
        }
    }

#pragma unroll
    for (int r = 0; r < 8; ++r) {
        int gr = rowBase + rg * 8 + r;
        if (gr < N_NODES) {
            ushort4 o;
            o.x = f2bf(acc[r][0]);
            o.y = f2bf(acc[r][1]);
            o.z = f2bf(acc[r][2]);
            o.w = f2bf(acc[r][3]);
            *(ushort4*)&H[(size_t)gr * D + c0] = o;
        }
    }
}

// ---------------- fused aggregation: self + gather + bias + relu ----------------
// one wave per node; h is bf16 row-major (uint = 2 feats per lane).
// Edge loop processes MASKED GROUPS OF 8 independent gathers (latency hiding).
template <bool OUT_BF>
__global__ __launch_bounds__(256) void k_agg(const unsigned* __restrict__ h,
                                             const float* __restrict__ dinv,
                                             const int* __restrict__ offs,
                                             const int* __restrict__ csr_src,
                                             const float* __restrict__ csr_w,
                                             const float* __restrict__ bias,
                                             void* __restrict__ out) {
    int wid = threadIdx.x >> 6;
    int lane = threadIdx.x & 63;
    int node = blockIdx.x * 4 + wid;
    if (node >= N_NODES) return;
    float dn = dinv[node];
    dn *= dn;
    unsigned sv = h[(size_t)node * 64 + lane];
    float ax = bf2f_lo(sv) * dn, ay = bf2f_hi(sv) * dn;
    int p0 = offs[node], p1 = offs[node + 1];

    for (int p = p0; p < p1; p += 8) {
        int ii[8];
        float ww[8];
#pragma unroll
        for (int k = 0; k < 8; ++k) {
            int pe = p + k;
            bool v = pe < p1;
            ii[k] = v ? pe : p0;            // p0 < p1 inside loop -> safe
            ww[k] = v ? csr_w[p + k] : 0.f; // note: reads csr_w[ii[k]] when valid
        }
        int ss[8];
#pragma unroll
        for (int k = 0; k < 8; ++k) ss[k] = csr_src[ii[k]];
        unsigned hh[8];
#pragma unroll
        for (int k = 0; k < 8; ++k) hh[k] = h[(size_t)ss[k] * 64 + lane];
#pragma unroll
        for (int k = 0; k < 8; ++k) {
            ax += ww[k] * bf2f_lo(hh[k]);
            ay += ww[k] * bf2f_hi(hh[k]);
        }
    }

    float2 bb = *(const float2*)&bias[lane * 2];
    ax = fmaxf(ax + bb.x, 0.f);
    ay = fmaxf(ay + bb.y, 0.f);
    if (OUT_BF) {
        unsigned o = (unsigned)f2bf(ax) | ((unsigned)f2bf(ay) << 16);
        ((unsigned*)out)[(size_t)node * 64 + lane] = o;
    } else {
        *(float2*)&((float*)out)[(size_t)node * D + lane * 2] = make_float2(ax, ay);
    }
}

// ---------------- final: res[l] = sum_k o2[a][k]*o2[b][k]*w[k] + c ----------------
__global__ void k_final(const int* __restrict__ eli, const unsigned* __restrict__ o2,
                        const float* __restrict__ wv, const float* __restrict__ cval,
                        float* __restrict__ res) {
    unsigned g = blockIdx.x * 256 + threadIdx.x;
    int l = g >> 6;
    int t = g & 63;
    if (l < N_LABEL) {
        int a = eli[l];
        int b = eli[N_LABEL + l];
        unsigned ua = o2[(size_t)a * 64 + t];
        unsigned ub = o2[(size_t)b * 64 + t];
        float2 w2 = *(const float2*)&wv[t * 2];
        float s = bf2f_lo(ua) * bf2f_lo(ub) * w2.x + bf2f_hi(ua) * bf2f_hi(ub) * w2.y;
#pragma unroll
        for (int st = 32; st > 0; st >>= 1) s += __shfl_down(s, st, 64);
        if (t == 0) res[l] = s + *cval;
    }
}

extern "C" void kernel_launch(void* const* d_in, const int* in_sizes, int n_in,
                              void* d_out, int out_size, void* d_ws, size_t ws_size,
                              hipStream_t stream) {
    const float* x    = (const float*)d_in[0];
    const int*   ei   = (const int*)d_in[1];
    const float* ew   = (const float*)d_in[2];
    const int*   eli  = (const int*)d_in[3];
    const float* W1   = (const float*)d_in[4];
    const float* b1   = (const float*)d_in[5];
    const float* W2   = (const float*)d_in[6];
    const float* b2   = (const float*)d_in[7];
    const float* linW = (const float*)d_in[8];
    const float* linb = (const float*)d_in[9];
    float* res = (float*)d_out;

    // workspace layout (16B alignment maintained for all row buffers)
    float*    ws      = (float*)d_ws;
    float*    dinv    = ws;                              // N
    int*      offs    = (int*)(dinv + N_NODES);          // N+4
    int*      bsum    = offs + N_NODES + 4;              // 512
    int*      csr_src = bsum + 512;                      // E
    float*    csr_w   = (float*)(csr_src + N_EDGES);     // E (raw, then normalized)
    unsigned* h_bf    = (unsigned*)(csr_w + N_EDGES);    // N*64 uints (bf16 h)
    float*    agg     = (float*)(h_bf + (size_t)N_NODES * 64);   // N*D f32
    unsigned* out2    = (unsigned*)(agg + (size_t)N_NODES * D);  // N*64 uints
    float*    wv      = (float*)(out2 + (size_t)N_NODES * 64);   // D
    float*    cval    = wv + D;                          // 1
    int*      rank    = (int*)agg;  // E ints, dead before agg is written

    k_prep<<<1, 128, 0, stream>>>(linW, linb, wv, cval);

    // CSR counts (rank-returning), scan, atomic-free scatter
    k_init<<<(N_NODES + 4 + 255) / 256, 256, 0, stream>>>(offs);
    k_count<<<(N_EDGES + 255) / 256, 256, 0, stream>>>(ei, offs, rank);
    k_scan1<<<SCAN_BLOCKS, 256, 0, stream>>>(offs, bsum);
    k_scan2<<<1, 512, 0, stream>>>(bsum);
    k_scan3<<<SCAN_BLOCKS, 256, 0, stream>>>(offs, bsum);
    k_scatter<<<(N_EDGES + 255) / 256, 256, 0, stream>>>(ei, ew, offs, rank,
                                                         csr_src, csr_w);

    // degrees from CSR (no atomics), then normalize weights in place
    k_degdinv<<<(N_NODES + 255) / 256, 256, 0, stream>>>(offs, csr_w, dinv);
    k_normw<<<(N_NODES + 255) / 256, 256, 0, stream>>>(offs, csr_src, csr_w, dinv);

    // layer 1: h = x@W1 (bf16), agg = A_norm·h + b1, relu (fp32 out)
    k_gemm<<<(N_NODES + 63) / 64, 256, 0, stream>>>(x, W1, (unsigned short*)h_bf);
    k_agg<false><<<(N_NODES + 3) / 4, 256, 0, stream>>>(h_bf, dinv, offs, csr_src,
                                                        csr_w, b1, agg);

    // layer 2: h = agg@W2 (bf16), out2 = A_norm·h + b2, relu (bf16 out)
    k_gemm<<<(N_NODES + 63) / 64, 256, 0, stream>>>(agg, W2, (unsigned short*)h_bf);
    k_agg<true><<<(N_NODES + 3) / 4, 256, 0, stream>>>(h_bf, dinv, offs, csr_src,
                                                       csr_w, b2, out2);

    // final
    k_final<<<(N_LABEL * 64 + 255) / 256, 256, 0, stream>>>(eli, out2, wv, cval, res);
}

// Round 8
// 471.428 us; speedup vs baseline: 1.9971x; 1.0248x over previous
//
#include <hip/hip_runtime.h>

#define N_NODES 100000
#define N_EDGES 1600000
#define N_LABEL 200000
#define D 128

#define SCAN_BLOCKS ((N_NODES + 255) / 256)   // 391

// ---- bf16 helpers (round-to-nearest-even) ----
static __device__ __forceinline__ unsigned short f2bf(float f) {
    unsigned u = __float_as_uint(f);
    u += 0x7fffu + ((u >> 16) & 1u);
    return (unsigned short)(u >> 16);
}
static __device__ __forceinline__ float bf2f_lo(unsigned p) {
    return __uint_as_float(p << 16);
}
static __device__ __forceinline__ float bf2f_hi(unsigned p) {
    return __uint_as_float(p & 0xffff0000u);
}

// ---------------- prep: w = rowsum(lin_W), c = sum(lin_b) ----------------
__global__ void k_prep(const float* __restrict__ linW, const float* __restrict__ linb,
                       float* __restrict__ wv, float* __restrict__ cval) {
    int t = threadIdx.x;  // 128 threads
    float s = 0.f;
    for (int j = 0; j < D; ++j) s += linW[t * D + j];
    wv[t] = s;
    __shared__ float red[128];
    red[t] = linb[t];
    __syncthreads();
    for (int st = 64; st > 0; st >>= 1) {
        if (t < st) red[t] += red[t + st];
        __syncthreads();
    }
    if (t == 0) *cval = red[0];
}

// ---------------- init: offs=0 ----------------
__global__ void k_init(int* __restrict__ offs) {
    int i = blockIdx.x * 256 + threadIdx.x;
    if (i < N_NODES + 4) offs[i] = 0;
}

// count in-degree; the SAME atomic returns each edge's rank within its dst
__global__ void k_count(const int* __restrict__ ei, int* __restrict__ cnt,
                        int* __restrict__ rank) {
    int e = blockIdx.x * 256 + threadIdx.x;
    if (e < N_EDGES) rank[e] = atomicAdd(&cnt[ei[N_EDGES + e]], 1);
}

// ---------------- CSR build: scan ----------------
__global__ void k_scan1(int* __restrict__ offs, int* __restrict__ bsum) {
    __shared__ int sm[256];
    int tid = threadIdx.x;
    int i = blockIdx.x * 256 + tid;
    int v = (i < N_NODES) ? offs[i] : 0;
    sm[tid] = v;
    __syncthreads();
    for (int st = 1; st < 256; st <<= 1) {
        int add = (tid >= st) ? sm[tid - st] : 0;
        __syncthreads();
        sm[tid] += add;
        __syncthreads();
    }
    if (i < N_NODES) offs[i] = sm[tid] - v;  // exclusive
    if (tid == 255) bsum[blockIdx.x] = sm[255];
}

__global__ void k_scan2(int* __restrict__ bsum) {
    __shared__ int sm[512];
    int tid = threadIdx.x;
    int v = (tid < SCAN_BLOCKS) ? bsum[tid] : 0;
    sm[tid] = v;
    __syncthreads();
    for (int st = 1; st < 512; st <<= 1) {
        int add = (tid >= st) ? sm[tid - st] : 0;
        __syncthreads();
        sm[tid] += add;
        __syncthreads();
    }
    if (tid < SCAN_BLOCKS) bsum[tid] = sm[tid] - v;  // exclusive
}

__global__ void k_scan3(int* __restrict__ offs, const int* __restrict__ bsum) {
    int i = blockIdx.x * 256 + threadIdx.x;
    if (i < N_NODES) offs[i] += bsum[i >> 8];
    if (i == 0) offs[N_NODES] = N_EDGES;
}

// atomic-free scatter: pos = offs[dst] + rank[e]
// csr record: (src*64, raw weight bits) in one int2 (single 8B store)
__global__ void k_scatter(const int* __restrict__ ei, const float* __restrict__ ew,
                          const int* __restrict__ offs, const int* __restrict__ rank,
                          int2* __restrict__ csr) {
    int e = blockIdx.x * 256 + threadIdx.x;
    if (e < N_EDGES) {
        int d = ei[N_EDGES + e];
        int pos = offs[d] + rank[e];
        csr[pos] = make_int2(ei[e] << 6, __float_as_int(ew[e]));
    }
}

// deg[i] = 1 + sum of raw weights over i's CSR rows -> dinv (no atomics)
__global__ void k_degdinv(const int* __restrict__ offs, const int2* __restrict__ csr,
                          float* __restrict__ dinv) {
    int i = blockIdx.x * 256 + threadIdx.x;
    if (i < N_NODES) {
        int p0 = offs[i], p1 = offs[i + 1];
        float s = 1.0f;  // self loop
        for (int p = p0; p < p1; ++p) s += __int_as_float(csr[p].y);
        dinv[i] = rsqrtf(s);
    }
}

// normalize weight word in place: w = raw * dinv[src] * dinv[dst]
__global__ void k_normw(const int* __restrict__ offs, int2* __restrict__ csr,
                        const float* __restrict__ dinv) {
    int i = blockIdx.x * 256 + threadIdx.x;
    if (i < N_NODES) {
        int p0 = offs[i], p1 = offs[i + 1];
        float dv = dinv[i];
        for (int p = p0; p < p1; ++p) {
            int2 c = csr[p];
            float w = __int_as_float(c.y) * dinv[c.x >> 6] * dv;
            ((int*)csr)[2 * p + 1] = __float_as_int(w);
        }
    }
}

// ---------------- GEMM: H(bf16) = X(f32) @ W(f32) ----------------
__global__ __launch_bounds__(256) void k_gemm(const float* __restrict__ X,
                                              const float* __restrict__ W,
                                              unsigned short* __restrict__ H) {
    __shared__ float xs[64][128];
    __shared__ float ws[16][128];
    int tid = threadIdx.x;
    int rowBase = blockIdx.x * 64;

#pragma unroll
    for (int i = 0; i < 8; ++i) {
        int idx = tid + i * 256;
        int r = idx >> 5;
        int cc = (idx & 31) * 4;
        int gr = rowBase + r;
        float4 v = make_float4(0.f, 0.f, 0.f, 0.f);
        if (gr < N_NODES) v = *(const float4*)&X[(size_t)gr * D + cc];
        *(float4*)&xs[r][cc] = v;
    }

    int rg = tid >> 5;       // 0..7
    int cg = tid & 31;       // 0..31
    int c0 = cg * 4;
    float acc[8][4] = {};

    for (int k0 = 0; k0 < D; k0 += 16) {
        __syncthreads();  // protect ws reuse (covers xs staging on first iter)
#pragma unroll
        for (int i = 0; i < 2; ++i) {
            int idx = tid + i * 256;
            int r = idx >> 5;
            int cc = (idx & 31) * 4;
            *(float4*)&ws[r][cc] = *(const float4*)&W[(k0 + r) * D + cc];
        }
        __syncthreads();
#pragma unroll
        for (int kk = 0; kk < 16; kk += 4) {
            float4 w0 = *(float4*)&ws[kk + 0][c0];
            float4 w1 = *(float4*)&ws[kk + 1][c0];
            float4 w2 = *(float4*)&ws[kk + 2][c0];
            float4 w3 = *(float4*)&ws[kk + 3][c0];
#pragma unroll
            for (int r = 0; r < 8; ++r) {
                float4 xv = *(float4*)&xs[rg * 8 + r][k0 + kk];
                acc[r][0] += xv.x * w0.x + xv.y * w1.x + xv.z * w2.x + xv.w * w3.x;
                acc[r][1] += xv.x * w0.y + xv.y * w1.y + xv.z * w2.y + xv.w * w3.y;
                acc[r][2] += xv.x * w0.z + xv.y * w1.z + xv.z * w2.z + xv.w * w3.z;
                acc[r][3] += xv.x * w0.w + xv.y * w1.w + xv.z * w2.w + xv.w * w3.w;
            }
        }
    }

#pragma unroll
    for (int r = 0; r < 8; ++r) {
        int gr = rowBase + rg * 8 + r;
        if (gr < N_NODES) {
            ushort4 o;
            o.x = f2bf(acc[r][0]);
            o.y = f2bf(acc[r][1]);
            o.z = f2bf(acc[r][2]);
            o.w = f2bf(acc[r][3]);
            *(ushort4*)&H[(size_t)gr * D + c0] = o;
        }
    }
}

// ---------------- fused aggregation: self + gather + bias + relu ----------------
// one wave per node. Lane split: eh = lane>>5 (edge parity), fl = lane&31
// (feature quad: feats 4fl..4fl+3 = uints 2fl,2fl+1). Each iteration covers
// 16 edges with 8 independent int2 CSR loads + 8 independent dwordx2 gathers
// per lane. Parity partials merged once at the end via shfl_xor(32).
template <bool OUT_BF>
__global__ __launch_bounds__(256) void k_agg(const unsigned* __restrict__ h,
                                             const float* __restrict__ dinv,
                                             const int* __restrict__ offs,
                                             const int2* __restrict__ csr,
                                             const float* __restrict__ bias,
                                             void* __restrict__ out) {
    int wid = threadIdx.x >> 6;
    int lane = threadIdx.x & 63;
    int node = blockIdx.x * 4 + wid;
    if (node >= N_NODES) return;

    int eh = lane >> 5;   // edge parity 0/1
    int fl = lane & 31;   // feature quad 0..31

    float a0 = 0.f, a1 = 0.f, a2 = 0.f, a3 = 0.f;
    int p0 = offs[node], p1 = offs[node + 1];

    for (int p = p0; p < p1; p += 16) {
        int2 cc[8];
        float ww[8];
#pragma unroll
        for (int k = 0; k < 8; ++k) {
            int pe = p + (k << 1) + eh;
            bool v = pe < p1;
            cc[k] = csr[v ? pe : p0];       // p0 < p1 inside loop -> safe
            ww[k] = v ? __int_as_float(cc[k].y) : 0.f;
        }
        uint2 hh[8];
#pragma unroll
        for (int k = 0; k < 8; ++k)
            hh[k] = *(const uint2*)&h[(size_t)(unsigned)cc[k].x + fl * 2];
#pragma unroll
        for (int k = 0; k < 8; ++k) {
            a0 += ww[k] * bf2f_lo(hh[k].x);
            a1 += ww[k] * bf2f_hi(hh[k].x);
            a2 += ww[k] * bf2f_lo(hh[k].y);
            a3 += ww[k] * bf2f_hi(hh[k].y);
        }
    }

    // merge parity halves (lane L += lane L^32)
    a0 += __shfl_xor(a0, 32, 64);
    a1 += __shfl_xor(a1, 32, 64);
    a2 += __shfl_xor(a2, 32, 64);
    a3 += __shfl_xor(a3, 32, 64);

    if (eh == 0) {
        float dn = dinv[node];
        dn *= dn;
        uint2 sv = *(const uint2*)&h[(size_t)node * 64 + fl * 2];
        a0 += dn * bf2f_lo(sv.x);
        a1 += dn * bf2f_hi(sv.x);
        a2 += dn * bf2f_lo(sv.y);
        a3 += dn * bf2f_hi(sv.y);
        float4 bb = *(const float4*)&bias[fl * 4];
        a0 = fmaxf(a0 + bb.x, 0.f);
        a1 = fmaxf(a1 + bb.y, 0.f);
        a2 = fmaxf(a2 + bb.z, 0.f);
        a3 = fmaxf(a3 + bb.w, 0.f);
        if (OUT_BF) {
            uint2 o;
            o.x = (unsigned)f2bf(a0) | ((unsigned)f2bf(a1) << 16);
            o.y = (unsigned)f2bf(a2) | ((unsigned)f2bf(a3) << 16);
            *(uint2*)&((unsigned*)out)[(size_t)node * 64 + fl * 2] = o;
        } else {
            *(float4*)&((float*)out)[(size_t)node * D + fl * 4] =
                make_float4(a0, a1, a2, a3);
        }
    }
}

// ---------------- final: res[l] = sum_k o2[a][k]*o2[b][k]*w[k] + c ----------------
__global__ void k_final(const int* __restrict__ eli, const unsigned* __restrict__ o2,
                        const float* __restrict__ wv, const float* __restrict__ cval,
                        float* __restrict__ res) {
    unsigned g = blockIdx.x * 256 + threadIdx.x;
    int l = g >> 6;
    int t = g & 63;
    if (l < N_LABEL) {
        int a = eli[l];
        int b = eli[N_LABEL + l];
        unsigned ua = o2[(size_t)a * 64 + t];
        unsigned ub = o2[(size_t)b * 64 + t];
        float2 w2 = *(const float2*)&wv[t * 2];
        float s = bf2f_lo(ua) * bf2f_lo(ub) * w2.x + bf2f_hi(ua) * bf2f_hi(ub) * w2.y;
#pragma unroll
        for (int st = 32; st > 0; st >>= 1) s += __shfl_down(s, st, 64);
        if (t == 0) res[l] = s + *cval;
    }
}

extern "C" void kernel_launch(void* const* d_in, const int* in_sizes, int n_in,
                              void* d_out, int out_size, void* d_ws, size_t ws_size,
                              hipStream_t stream) {
    const float* x    = (const float*)d_in[0];
    const int*   ei   = (const int*)d_in[1];
    const float* ew   = (const float*)d_in[2];
    const int*   eli  = (const int*)d_in[3];
    const float* W1   = (const float*)d_in[4];
    const float* b1   = (const float*)d_in[5];
    const float* W2   = (const float*)d_in[6];
    const float* b2   = (const float*)d_in[7];
    const float* linW = (const float*)d_in[8];
    const float* linb = (const float*)d_in[9];
    float* res = (float*)d_out;

    // workspace layout (int2 csr is 8B-aligned: 200516 ints before it = 8-mult)
    float*    ws      = (float*)d_ws;
    float*    dinv    = ws;                              // N
    int*      offs    = (int*)(dinv + N_NODES);          // N+4
    int*      bsum    = offs + N_NODES + 4;              // 512
    int2*     csr     = (int2*)(bsum + 512);             // E int2 (src*64, wbits)
    unsigned* h_bf    = (unsigned*)(csr + N_EDGES);      // N*64 uints (bf16 h)
    float*    agg     = (float*)(h_bf + (size_t)N_NODES * 64);   // N*D f32
    unsigned* out2    = (unsigned*)(agg + (size_t)N_NODES * D);  // N*64 uints
    float*    wv      = (float*)(out2 + (size_t)N_NODES * 64);   // D
    float*    cval    = wv + D;                          // 1
    int*      rank    = (int*)agg;  // E ints, dead before agg is written

    k_prep<<<1, 128, 0, stream>>>(linW, linb, wv, cval);

    // CSR counts (rank-returning), scan, atomic-free scatter
    k_init<<<(N_NODES + 4 + 255) / 256, 256, 0, stream>>>(offs);
    k_count<<<(N_EDGES + 255) / 256, 256, 0, stream>>>(ei, offs, rank);
    k_scan1<<<SCAN_BLOCKS, 256, 0, stream>>>(offs, bsum);
    k_scan2<<<1, 512, 0, stream>>>(bsum);
    k_scan3<<<SCAN_BLOCKS, 256, 0, stream>>>(offs, bsum);
    k_scatter<<<(N_EDGES + 255) / 256, 256, 0, stream>>>(ei, ew, offs, rank, csr);

    // degrees from CSR (no atomics), then normalize weights in place
    k_degdinv<<<(N_NODES + 255) / 256, 256, 0, stream>>>(offs, csr, dinv);
    k_normw<<<(N_NODES + 255) / 256, 256, 0, stream>>>(offs, csr, dinv);

    // layer 1: h = x@W1 (bf16), agg = A_norm·h + b1, relu (fp32 out)
    k_gemm<<<(N_NODES + 63) / 64, 256, 0, stream>>>(x, W1, (unsigned short*)h_bf);
    k_agg<false><<<(N_NODES + 3) / 4, 256, 0, stream>>>(h_bf, dinv, offs, csr, b1, agg);

    // layer 2: h = agg@W2 (bf16), out2 = A_norm·h + b2, relu (bf16 out)
    k_gemm<<<(N_NODES + 63) / 64, 256, 0, stream>>>(agg, W2, (unsigned short*)h_bf);
    k_agg<true><<<(N_NODES + 3) / 4, 256, 0, stream>>>(h_bf, dinv, offs, csr, b2, out2);

    // final
    k_final<<<(N_LABEL * 64 + 255) / 256, 256, 0, stream>>>(eli, out2, wv, cval, res);
}

// Round 9
// 373.143 us; speedup vs baseline: 2.5231x; 1.2634x over previous
//
#include <hip/hip_runtime.h>

#define N_NODES 100000
#define N_EDGES 1600000
#define N_LABEL 200000
#define D 128

#define SCAN_BLOCKS ((N_NODES + 255) / 256)   // 391

typedef __attribute__((ext_vector_type(8))) short short8;
typedef __attribute__((ext_vector_type(4))) float f32x4;

// ---- bf16 helpers (round-to-nearest-even) ----
static __device__ __forceinline__ unsigned short f2bf(float f) {
    unsigned u = __float_as_uint(f);
    u += 0x7fffu + ((u >> 16) & 1u);
    return (unsigned short)(u >> 16);
}
static __device__ __forceinline__ float bf2f_lo(unsigned p) {
    return __uint_as_float(p << 16);
}
static __device__ __forceinline__ float bf2f_hi(unsigned p) {
    return __uint_as_float(p & 0xffff0000u);
}

// ---------------- prep: w = rowsum(lin_W), c = sum(lin_b) ----------------
__global__ void k_prep(const float* __restrict__ linW, const float* __restrict__ linb,
                       float* __restrict__ wv, float* __restrict__ cval) {
    int t = threadIdx.x;  // 128 threads
    float s = 0.f;
    for (int j = 0; j < D; ++j) s += linW[t * D + j];
    wv[t] = s;
    __shared__ float red[128];
    red[t] = linb[t];
    __syncthreads();
    for (int st = 64; st > 0; st >>= 1) {
        if (t < st) red[t] += red[t + st];
        __syncthreads();
    }
    if (t == 0) *cval = red[0];
}

// transpose + bf16-convert a 128x128 weight: Wt[n][k] = bf16(W[k][n])
__global__ void k_prepw(const float* __restrict__ W, unsigned short* __restrict__ Wt) {
    int i = blockIdx.x * 256 + threadIdx.x;
    if (i < D * D) {
        int k = i >> 7, n = i & 127;
        Wt[n * D + k] = f2bf(W[i]);
    }
}

// ---------------- init: offs=0 ----------------
__global__ void k_init(int* __restrict__ offs) {
    int i = blockIdx.x * 256 + threadIdx.x;
    if (i < N_NODES + 4) offs[i] = 0;
}

// count in-degree; the SAME atomic returns each edge's rank within its dst
__global__ void k_count(const int* __restrict__ ei, int* __restrict__ cnt,
                        int* __restrict__ rank) {
    int e = blockIdx.x * 256 + threadIdx.x;
    if (e < N_EDGES) rank[e] = atomicAdd(&cnt[ei[N_EDGES + e]], 1);
}

// ---------------- CSR build: scan ----------------
__global__ void k_scan1(int* __restrict__ offs, int* __restrict__ bsum) {
    __shared__ int sm[256];
    int tid = threadIdx.x;
    int i = blockIdx.x * 256 + tid;
    int v = (i < N_NODES) ? offs[i] : 0;
    sm[tid] = v;
    __syncthreads();
    for (int st = 1; st < 256; st <<= 1) {
        int add = (tid >= st) ? sm[tid - st] : 0;
        __syncthreads();
        sm[tid] += add;
        __syncthreads();
    }
    if (i < N_NODES) offs[i] = sm[tid] - v;  // exclusive
    if (tid == 255) bsum[blockIdx.x] = sm[255];
}

__global__ void k_scan2(int* __restrict__ bsum) {
    __shared__ int sm[512];
    int tid = threadIdx.x;
    int v = (tid < SCAN_BLOCKS) ? bsum[tid] : 0;
    sm[tid] = v;
    __syncthreads();
    for (int st = 1; st < 512; st <<= 1) {
        int add = (tid >= st) ? sm[tid - st] : 0;
        __syncthreads();
        sm[tid] += add;
        __syncthreads();
    }
    if (tid < SCAN_BLOCKS) bsum[tid] = sm[tid] - v;  // exclusive
}

__global__ void k_scan3(int* __restrict__ offs, const int* __restrict__ bsum) {
    int i = blockIdx.x * 256 + threadIdx.x;
    if (i < N_NODES) offs[i] += bsum[i >> 8];
    if (i == 0) offs[N_NODES] = N_EDGES;
}

// atomic-free scatter: pos = offs[dst] + rank[e]
// csr record: (src*64, RAW weight bits) in one int2 (single 8B store)
__global__ void k_scatter(const int* __restrict__ ei, const float* __restrict__ ew,
                          const int* __restrict__ offs, const int* __restrict__ rank,
                          int2* __restrict__ csr) {
    int e = blockIdx.x * 256 + threadIdx.x;
    if (e < N_EDGES) {
        int d = ei[N_EDGES + e];
        int pos = offs[d] + rank[e];
        csr[pos] = make_int2(ei[e] << 6, __float_as_int(ew[e]));
    }
}

// deg[i] = 1 + sum of raw weights over i's CSR rows -> dinv (no atomics)
__global__ void k_degdinv(const int* __restrict__ offs, const int2* __restrict__ csr,
                          float* __restrict__ dinv) {
    int i = blockIdx.x * 256 + threadIdx.x;
    if (i < N_NODES) {
        int p0 = offs[i], p1 = offs[i + 1];
        float s = 1.0f;  // self loop
        for (int p = p0; p < p1; ++p) s += __int_as_float(csr[p].y);
        dinv[i] = rsqrtf(s);
    }
}

// ---------------- MFMA GEMM: H'(bf16) = dinv_row * (IN @ W) ----------------
// IN: fp32 (layer1 x) or bf16 (layer2 agg), row-major [N][128].
// Wt: bf16 transposed weight [n][k]. H: bf16 row-major [N][128], pre-scaled
// by dinv[row] (the h' = dinv*h folding that eliminates k_normw).
// Tile: 64 rows/block, 4 waves, wave = 16 rows x 128 cols.
// LDS row-major bf16 with XOR swizzle idx ^= (row&7)<<3 (ushort units).
// Frag (16x16x32): lane l: row/col = l&15, k = (l>>4)*4+j  and  +16 (two 8B chunks).
template <bool IN_F32>
__global__ __launch_bounds__(256) void k_gemm(const void* __restrict__ INp,
                                              const unsigned short* __restrict__ Wt,
                                              const float* __restrict__ dinv,
                                              unsigned short* __restrict__ H) {
    __shared__ unsigned short xs[64 * 128];
    __shared__ unsigned short wts[128 * 128];
    int tid = threadIdx.x;
    int rowBase = blockIdx.x * 64;

    // stage input tile (convert to bf16 if fp32)
#pragma unroll
    for (int i = 0; i < 4; ++i) {
        int idx = tid + i * 256;        // 1024 slots of 8 elems
        int r = idx >> 4;
        int kc = (idx & 15) << 3;
        int gr = rowBase + r;
        uint4 pk = make_uint4(0, 0, 0, 0);
        if (gr < N_NODES) {
            if (IN_F32) {
                const float* X = (const float*)INp;
                float4 v0 = *(const float4*)&X[(size_t)gr * D + kc];
                float4 v1 = *(const float4*)&X[(size_t)gr * D + kc + 4];
                pk.x = (unsigned)f2bf(v0.x) | ((unsigned)f2bf(v0.y) << 16);
                pk.y = (unsigned)f2bf(v0.z) | ((unsigned)f2bf(v0.w) << 16);
                pk.z = (unsigned)f2bf(v1.x) | ((unsigned)f2bf(v1.y) << 16);
                pk.w = (unsigned)f2bf(v1.z) | ((unsigned)f2bf(v1.w) << 16);
            } else {
                pk = *(const uint4*)&((const unsigned short*)INp)[(size_t)gr * D + kc];
            }
        }
        *(uint4*)&xs[(r * D + kc) ^ ((r & 7) << 3)] = pk;
    }
    // stage Wt (bf16 global, coalesced)
#pragma unroll
    for (int i = 0; i < 8; ++i) {
        int idx = tid + i * 256;        // 2048 slots
        int n = idx >> 4;
        int kc = (idx & 15) << 3;
        uint4 pk = *(const uint4*)&Wt[n * D + kc];
        *(uint4*)&wts[(n * D + kc) ^ ((n & 7) << 3)] = pk;
    }
    __syncthreads();

    int lane = tid & 63;
    int wrow = (tid >> 6) * 16;       // wave's row block within tile
    int l15 = lane & 15;
    int l4 = (lane >> 4) << 2;

    f32x4 acc[8] = {};
    union FragU { short8 v; uint2 u2[2]; };

#pragma unroll
    for (int kk = 0; kk < 4; ++kk) {
        int kb = kk * 32 + l4;
        int m = wrow + l15;
        FragU a;
        a.u2[0] = *(uint2*)&xs[(m * D + kb) ^ ((m & 7) << 3)];
        a.u2[1] = *(uint2*)&xs[(m * D + kb + 16) ^ ((m & 7) << 3)];
#pragma unroll
        for (int ct = 0; ct < 8; ++ct) {
            int n = ct * 16 + l15;
            FragU b;
            b.u2[0] = *(uint2*)&wts[(n * D + kb) ^ ((n & 7) << 3)];
            b.u2[1] = *(uint2*)&wts[(n * D + kb + 16) ^ ((n & 7) << 3)];
            acc[ct] = __builtin_amdgcn_mfma_f32_16x16x32_bf16(a.v, b.v, acc[ct], 0, 0, 0);
        }
    }

    // epilogue: scale by dinv[row], store bf16
    int rloc = wrow + l4;             // rows rloc..rloc+3, col l15 per tile
    float dn[4];
#pragma unroll
    for (int r = 0; r < 4; ++r) {
        int gr = rowBase + rloc + r;
        dn[r] = (gr < N_NODES) ? dinv[gr] : 0.f;
    }
#pragma unroll
    for (int ct = 0; ct < 8; ++ct) {
#pragma unroll
        for (int r = 0; r < 4; ++r) {
            int gr = rowBase + rloc + r;
            if (gr < N_NODES)
                H[(size_t)gr * D + ct * 16 + l15] = f2bf(acc[ct][r] * dn[r]);
        }
    }
}

// ---------------- fused aggregation: gather(h') + self + dinv + bias + relu ----
// h' is dinv-prescaled bf16. out[d] = relu(dinv[d]*(sum ew*h'[s] + h'[d]) + b).
// Lane split: eh = lane>>5 (edge parity), fl = lane&31 (feature quad).
__global__ __launch_bounds__(256) void k_agg(const unsigned* __restrict__ h,
                                             const float* __restrict__ dinv,
                                             const int* __restrict__ offs,
                                             const int2* __restrict__ csr,
                                             const float* __restrict__ bias,
                                             unsigned* __restrict__ out) {
    int wid = threadIdx.x >> 6;
    int lane = threadIdx.x & 63;
    int node = blockIdx.x * 4 + wid;
    if (node >= N_NODES) return;

    int eh = lane >> 5;   // edge parity 0/1
    int fl = lane & 31;   // feature quad 0..31

    float a0 = 0.f, a1 = 0.f, a2 = 0.f, a3 = 0.f;
    int p0 = offs[node], p1 = offs[node + 1];

    for (int p = p0; p < p1; p += 16) {
        int2 cc[8];
        float ww[8];
#pragma unroll
        for (int k = 0; k < 8; ++k) {
            int pe = p + (k << 1) + eh;
            bool v = pe < p1;
            cc[k] = csr[v ? pe : p0];       // p0 < p1 inside loop -> safe
            ww[k] = v ? __int_as_float(cc[k].y) : 0.f;
        }
        uint2 hh[8];
#pragma unroll
        for (int k = 0; k < 8; ++k)
            hh[k] = *(const uint2*)&h[(size_t)(unsigned)cc[k].x + fl * 2];
#pragma unroll
        for (int k = 0; k < 8; ++k) {
            a0 += ww[k] * bf2f_lo(hh[k].x);
            a1 += ww[k] * bf2f_hi(hh[k].x);
            a2 += ww[k] * bf2f_lo(hh[k].y);
            a3 += ww[k] * bf2f_hi(hh[k].y);
        }
    }

    // merge parity halves (lane L += lane L^32)
    a0 += __shfl_xor(a0, 32, 64);
    a1 += __shfl_xor(a1, 32, 64);
    a2 += __shfl_xor(a2, 32, 64);
    a3 += __shfl_xor(a3, 32, 64);

    if (eh == 0) {
        uint2 sv = *(const uint2*)&h[(size_t)node * 64 + fl * 2];
        a0 += bf2f_lo(sv.x);
        a1 += bf2f_hi(sv.x);
        a2 += bf2f_lo(sv.y);
        a3 += bf2f_hi(sv.y);
        float dn = dinv[node];
        float4 bb = *(const float4*)&bias[fl * 4];
        a0 = fmaxf(a0 * dn + bb.x, 0.f);
        a1 = fmaxf(a1 * dn + bb.y, 0.f);
        a2 = fmaxf(a2 * dn + bb.z, 0.f);
        a3 = fmaxf(a3 * dn + bb.w, 0.f);
        uint2 o;
        o.x = (unsigned)f2bf(a0) | ((unsigned)f2bf(a1) << 16);
        o.y = (unsigned)f2bf(a2) | ((unsigned)f2bf(a3) << 16);
        *(uint2*)&out[(size_t)node * 64 + fl * 2] = o;
    }
}

// ---------------- final: res[l] = sum_k o2[a][k]*o2[b][k]*w[k] + c ----------------
__global__ void k_final(const int* __restrict__ eli, const unsigned* __restrict__ o2,
                        const float* __restrict__ wv, const float* __restrict__ cval,
                        float* __restrict__ res) {
    unsigned g = blockIdx.x * 256 + threadIdx.x;
    int l = g >> 6;
    int t = g & 63;
    if (l < N_LABEL) {
        int a = eli[l];
        int b = eli[N_LABEL + l];
        unsigned ua = o2[(size_t)a * 64 + t];
        unsigned ub = o2[(size_t)b * 64 + t];
        float2 w2 = *(const float2*)&wv[t * 2];
        float s = bf2f_lo(ua) * bf2f_lo(ub) * w2.x + bf2f_hi(ua) * bf2f_hi(ub) * w2.y;
#pragma unroll
        for (int st = 32; st > 0; st >>= 1) s += __shfl_down(s, st, 64);
        if (t == 0) res[l] = s + *cval;
    }
}

extern "C" void kernel_launch(void* const* d_in, const int* in_sizes, int n_in,
                              void* d_out, int out_size, void* d_ws, size_t ws_size,
                              hipStream_t stream) {
    const float* x    = (const float*)d_in[0];
    const int*   ei   = (const int*)d_in[1];
    const float* ew   = (const float*)d_in[2];
    const int*   eli  = (const int*)d_in[3];
    const float* W1   = (const float*)d_in[4];
    const float* b1   = (const float*)d_in[5];
    const float* W2   = (const float*)d_in[6];
    const float* b2   = (const float*)d_in[7];
    const float* linW = (const float*)d_in[8];
    const float* linb = (const float*)d_in[9];
    float* res = (float*)d_out;

    // workspace layout (csr 8B-aligned: 200516 ints before it)
    float*          ws    = (float*)d_ws;
    float*          dinv  = ws;                              // N
    int*            offs  = (int*)(dinv + N_NODES);          // N+4
    int*            bsum  = offs + N_NODES + 4;              // 512
    int2*           csr   = (int2*)(bsum + 512);             // E int2 (src*64, raw w)
    unsigned*       h_bf  = (unsigned*)(csr + N_EDGES);      // N*64 uints (bf16 h')
    unsigned*       agg   = h_bf + (size_t)N_NODES * 64;     // N*64 uints (bf16)
    unsigned*       out2  = agg + (size_t)N_NODES * 64;      // N*64 uints (bf16)
    float*          wv    = (float*)(out2 + (size_t)N_NODES * 64);  // D
    float*          cval  = wv + D;                          // 1
    unsigned short* w1t   = (unsigned short*)(cval + 1);     // D*D bf16
    unsigned short* w2t   = w1t + D * D;                     // D*D bf16
    int*            rank  = (int*)agg;  // E ints, dead before agg is written

    k_prep<<<1, 128, 0, stream>>>(linW, linb, wv, cval);
    k_prepw<<<64, 256, 0, stream>>>(W1, w1t);
    k_prepw<<<64, 256, 0, stream>>>(W2, w2t);

    // CSR counts (rank-returning), scan, atomic-free scatter, degrees
    k_init<<<(N_NODES + 4 + 255) / 256, 256, 0, stream>>>(offs);
    k_count<<<(N_EDGES + 255) / 256, 256, 0, stream>>>(ei, offs, rank);
    k_scan1<<<SCAN_BLOCKS, 256, 0, stream>>>(offs, bsum);
    k_scan2<<<1, 512, 0, stream>>>(bsum);
    k_scan3<<<SCAN_BLOCKS, 256, 0, stream>>>(offs, bsum);
    k_scatter<<<(N_EDGES + 255) / 256, 256, 0, stream>>>(ei, ew, offs, rank, csr);
    k_degdinv<<<(N_NODES + 255) / 256, 256, 0, stream>>>(offs, csr, dinv);

    const int GB = (N_NODES + 63) / 64;

    // layer 1: h' = dinv*(x@W1) bf16 via MFMA; agg = relu(dinv*(A·h'+h') + b1) bf16
    k_gemm<true><<<GB, 256, 0, stream>>>(x, w1t, dinv, (unsigned short*)h_bf);
    k_agg<<<(N_NODES + 3) / 4, 256, 0, stream>>>(h_bf, dinv, offs, csr, b1, agg);

    // layer 2
    k_gemm<false><<<GB, 256, 0, stream>>>(agg, w2t, dinv, (unsigned short*)h_bf);
    k_agg<<<(N_NODES + 3) / 4, 256, 0, stream>>>(h_bf, dinv, offs, csr, b2, out2);

    // final
    k_final<<<(N_LABEL * 64 + 255) / 256, 256, 0, stream>>>(eli, out2, wv, cval, res);
}